// Round 1
// baseline (774.763 us; speedup 1.0000x reference)
//
#include <hip/hip_runtime.h>
#include <hip/hip_bf16.h>
#include <math.h>

// LinearAttention fused pipeline, fp32 baseline.
// dims: B=16, C=256, H=W=64 (n=4096), HEADS=8, dh=32, HID=256, 3*HID=768.
//
// ws layout (bytes):
//   qkv    @ 0          : 16*768*4096*4 = 201,326,592
//   kmax   @ 201326592  : 4096*4
//   krecip @ 201342976  : 4096*4
//   part   @ 201359360  : 128*8*1024*4 = 4,194,304
//   ctx    @ 205553664  : 128*1024*4   = 524,288
//   total ~206 MB

#define HEADS 8
#define DH 32
#define HID 256
#define CIN 256
#define NBATCH 16
#define NPIX 4096
#define O3 768
#define LN_EPS 1e-5f

// ---------------- K1: QKV GEMM (fp32) ----------------
// qkv[b][o][p] = sum_c w[o*CIN+c] * x[(b*CIN+c)*NPIX + p]
#define BM 64
#define BN 64
#define BK 16
#define LDW 68   // pad: rows 16B-aligned (68*4=272 bytes), breaks bank aliasing

__global__ __launch_bounds__(256) void qkv_gemm(
    const float* __restrict__ x, const float* __restrict__ w,
    float* __restrict__ qkv)
{
    __shared__ float Ws[BK][LDW];
    __shared__ float Xs[BK][LDW];
    const int t  = threadIdx.x;
    const int p0 = blockIdx.x * BN;
    const int o0 = blockIdx.y * BM;
    const int b  = blockIdx.z;
    const int tm = t >> 4;   // 0..15 (o groups of 4)
    const int tn = t & 15;   // 0..15 (p groups of 4)

    float acc[4][4] = {};
    const float* xb = x + (size_t)b * CIN * NPIX;

    for (int c0 = 0; c0 < CIN; c0 += BK) {
        #pragma unroll
        for (int r = 0; r < 4; ++r) {          // W tile: 16 contiguous c per o-row
            int om = r * 16 + (t >> 4);
            int kk = t & 15;
            Ws[kk][om] = w[(size_t)(o0 + om) * CIN + c0 + kk];
        }
        #pragma unroll
        for (int r = 0; r < 4; ++r) {          // X tile: 64 contiguous p per c-row
            int kk = r * 4 + (t >> 6);
            int pm = t & 63;
            Xs[kk][pm] = xb[(size_t)(c0 + kk) * NPIX + p0 + pm];
        }
        __syncthreads();
        #pragma unroll
        for (int kk = 0; kk < BK; ++kk) {
            const float4 a4 = *(const float4*)&Ws[kk][tm * 4];
            const float4 b4 = *(const float4*)&Xs[kk][tn * 4];
            const float av[4] = {a4.x, a4.y, a4.z, a4.w};
            const float bv[4] = {b4.x, b4.y, b4.z, b4.w};
            #pragma unroll
            for (int i = 0; i < 4; ++i)
                #pragma unroll
                for (int j = 0; j < 4; ++j)
                    acc[i][j] += av[i] * bv[j];
        }
        __syncthreads();
    }
    float* outp = qkv + (size_t)b * O3 * NPIX;
    #pragma unroll
    for (int i = 0; i < 4; ++i) {
        float4 s = make_float4(acc[i][0], acc[i][1], acc[i][2], acc[i][3]);
        *(float4*)&outp[(size_t)(o0 + tm * 4 + i) * NPIX + p0 + tn * 4] = s;
    }
}

// ---------------- K2: k-softmax row stats ----------------
// one block per (b, h*32+d) row of k; stores rowmax and 1/(sumexp * n)
__global__ __launch_bounds__(256) void ksoftmax_stats(
    const float* __restrict__ qkv,
    float* __restrict__ kmax, float* __restrict__ krecip)
{
    const int row = blockIdx.x;                 // 0..4095 = b*256 + cd
    const int b = row >> 8, cd = row & 255;
    const float* kp = qkv + ((size_t)b * O3 + HID + cd) * NPIX;
    const int t = threadIdx.x;
    float vals[16];
    float m = -1e30f;
    #pragma unroll
    for (int i = 0; i < 16; ++i) { vals[i] = kp[t + i * 256]; m = fmaxf(m, vals[i]); }
    #pragma unroll
    for (int off = 32; off > 0; off >>= 1) m = fmaxf(m, __shfl_xor(m, off));
    __shared__ float red[8];
    if ((t & 63) == 0) red[t >> 6] = m;
    __syncthreads();
    m = fmaxf(fmaxf(red[0], red[1]), fmaxf(red[2], red[3]));
    float s = 0.f;
    #pragma unroll
    for (int i = 0; i < 16; ++i) s += __expf(vals[i] - m);
    #pragma unroll
    for (int off = 32; off > 0; off >>= 1) s += __shfl_xor(s, off);
    __syncthreads();
    if ((t & 63) == 0) red[4 + (t >> 6)] = s;
    __syncthreads();
    if (t == 0) {
        float S = red[4] + red[5] + red[6] + red[7];
        kmax[row] = m;
        krecip[row] = 1.0f / (S * (float)NPIX);   // folds v/n into the k-softmax scale
    }
}

// ---------------- K3: context partials ----------------
// part[bh][seg][d][e] = sum_{p in seg} softk[d,p] * v[e,p]
#define CSEG 512
#define CCH 64
__global__ __launch_bounds__(256) void ctx_partial(
    const float* __restrict__ qkv,
    const float* __restrict__ kmax, const float* __restrict__ krecip,
    float* __restrict__ part)
{
    const int seg = blockIdx.x;   // 0..7
    const int bh  = blockIdx.y;   // 0..127
    const int b = bh >> 3, h = bh & 7;
    const int t = threadIdx.x;
    __shared__ float kc[DH][65];      // row-major, scalar broadcast reads
    __shared__ float vt[CCH][36];     // transposed, float4 reads (36*4 % 16 == 0)
    const float* kbase = qkv + ((size_t)b * O3 + HID + h * DH) * NPIX;
    const float* vbase = qkv + ((size_t)b * O3 + 2 * HID + h * DH) * NPIX;
    const int d  = t >> 3;
    const int e0 = (t & 7) * 4;
    float acc0 = 0, acc1 = 0, acc2 = 0, acc3 = 0;

    for (int ch = 0; ch < CSEG / CCH; ++ch) {
        const int pb = seg * CSEG + ch * CCH;
        #pragma unroll
        for (int r = 0; r < 8; ++r) {
            int dd = r * 4 + (t >> 6);
            int pp = t & 63;
            float kv = kbase[(size_t)dd * NPIX + pb + pp];
            kc[dd][pp] = __expf(kv - kmax[bh * DH + dd]) * krecip[bh * DH + dd];
            vt[pp][dd] = vbase[(size_t)dd * NPIX + pb + pp];
        }
        __syncthreads();
        #pragma unroll
        for (int pp = 0; pp < CCH; ++pp) {
            float kd = kc[d][pp];
            float4 v4 = *(const float4*)&vt[pp][e0];
            acc0 += kd * v4.x; acc1 += kd * v4.y;
            acc2 += kd * v4.z; acc3 += kd * v4.w;
        }
        __syncthreads();
    }
    float* pp = part + ((size_t)(bh * 8 + seg) * DH + d) * DH + e0;
    pp[0] = acc0; pp[1] = acc1; pp[2] = acc2; pp[3] = acc3;
}

__global__ __launch_bounds__(256) void ctx_reduce(
    const float* __restrict__ part, float* __restrict__ ctx)
{
    const int bh = blockIdx.x;
    const int t = threadIdx.x;
    #pragma unroll
    for (int r = 0; r < 4; ++r) {
        int idx = r * 256 + t;
        float s = 0.f;
        #pragma unroll
        for (int sg = 0; sg < 8; ++sg) s += part[((size_t)bh * 8 + sg) * 1024 + idx];
        ctx[(size_t)bh * 1024 + idx] = s;
    }
}

// ---------------- K4: fused q-softmax + context matvec + out-proj + LN ----------------
#define PB 32
__global__ __launch_bounds__(256) void out_fused(
    const float* __restrict__ qkv, const float* __restrict__ ctx,
    const float* __restrict__ w_out, const float* __restrict__ b_out,
    const float* __restrict__ g, float* __restrict__ y)
{
    __shared__ float q_s[256][33];     // q tile [c][pl], pad for bank spread
    __shared__ float buf[9216];        // out_s [e][stride36] then ybuf [pl][stride257]
    __shared__ float g_s[256];
    __shared__ float mean_s[PB], rstd_s[PB];
    const int t  = threadIdx.x;
    const int p0 = blockIdx.x * PB;
    const int b  = blockIdx.y;
    const int h = t >> 5, d32 = t & 31;

    // ctx column for this thread's e = t: ctx[b,h][d][e32], d=0..31 -> registers
    float ctx_reg[DH];
    const float* cb = ctx + ((size_t)b * 8 + h) * 1024 + d32;
    #pragma unroll
    for (int d = 0; d < DH; ++d) ctx_reg[d] = cb[d * 32];

    g_s[t] = g[t];

    const float* qb = qkv + (size_t)b * O3 * NPIX;   // q = channels [0,256)
    #pragma unroll
    for (int r = 0; r < 32; ++r) {
        int c = r * 8 + (t >> 5);
        int pl = t & 31;
        q_s[c][pl] = qb[(size_t)c * NPIX + p0 + pl];
    }
    __syncthreads();

    const float scale = 0.17677669529663689f;   // dh^-0.5
    // phase 1: per position, q-softmax over d within 32-lane head group, then out[e]
    for (int pl = 0; pl < PB; ++pl) {
        float qv = q_s[t][pl];
        float m = qv;
        #pragma unroll
        for (int off = 16; off > 0; off >>= 1) m = fmaxf(m, __shfl_xor(m, off));
        float ex = __expf(qv - m);
        float s = ex;
        #pragma unroll
        for (int off = 16; off > 0; off >>= 1) s += __shfl_xor(s, off);
        float qs = ex * (scale / s);
        float oe = 0.f;
        #pragma unroll
        for (int d = 0; d < DH; ++d) oe += ctx_reg[d] * __shfl(qs, d, 32);
        buf[t * 36 + pl] = oe;          // out_s[e=t][pl]
    }
    __syncthreads();

    // phase 2: y[c=t][pl] = b_out[c] + sum_e w_out[c][e] * out_s[e][pl]
    float yacc[PB];
    {
        float bias = b_out[t];
        #pragma unroll
        for (int i = 0; i < PB; ++i) yacc[i] = bias;
    }
    const float* wrow = w_out + (size_t)t * HID;
    for (int e = 0; e < HID; ++e) {
        float wv = wrow[e];
        #pragma unroll
        for (int pq = 0; pq < 8; ++pq) {
            float4 o4 = *(const float4*)&buf[e * 36 + pq * 4];  // broadcast, 16B-aligned
            yacc[pq * 4 + 0] += wv * o4.x;
            yacc[pq * 4 + 1] += wv * o4.y;
            yacc[pq * 4 + 2] += wv * o4.z;
            yacc[pq * 4 + 3] += wv * o4.w;
        }
    }
    __syncthreads();                     // all out_s reads done; reuse buf as ybuf
    #pragma unroll
    for (int pl = 0; pl < PB; ++pl) buf[pl * 257 + t] = yacc[pl];
    __syncthreads();

    // phase 3: LN stats — 8 threads per position
    {
        int pl = t >> 3, j = t & 7;
        float s = 0.f, ss = 0.f;
        #pragma unroll
        for (int i = 0; i < 32; ++i) {
            float v = buf[pl * 257 + j + 8 * i];
            s += v; ss += v * v;
        }
        #pragma unroll
        for (int off = 4; off > 0; off >>= 1) { s += __shfl_xor(s, off); ss += __shfl_xor(ss, off); }
        if (j == 0) {
            float mean = s * (1.f / 256.f);
            float var  = ss * (1.f / 256.f) - mean * mean;
            mean_s[pl] = mean;
            rstd_s[pl] = rsqrtf(var + LN_EPS);
        }
    }
    __syncthreads();

    // phase 4: normalized coalesced write (32 lanes cover 32 contiguous p)
    float* yb = y + (size_t)b * CIN * NPIX + p0;
    #pragma unroll
    for (int kk = 0; kk < 32; ++kk) {
        int c = kk * 8 + (t >> 5);
        int pl = t & 31;
        float v = buf[pl * 257 + c];
        v = (v - mean_s[pl]) * rstd_s[pl] * g_s[c];
        yb[(size_t)c * NPIX + pl] = v;
    }
}

extern "C" void kernel_launch(void* const* d_in, const int* in_sizes, int n_in,
                              void* d_out, int out_size, void* d_ws, size_t ws_size,
                              hipStream_t stream) {
    const float* x     = (const float*)d_in[0];
    const float* w_qkv = (const float*)d_in[1];
    const float* w_out = (const float*)d_in[2];
    const float* b_out = (const float*)d_in[3];
    const float* g     = (const float*)d_in[4];
    float* y = (float*)d_out;

    char* ws = (char*)d_ws;
    float* qkv    = (float*)ws;                          // 201,326,592 B
    float* kmax   = (float*)(ws + 201326592);            // 16,384 B
    float* krecip = (float*)(ws + 201342976);            // 16,384 B
    float* part   = (float*)(ws + 201359360);            // 4,194,304 B
    float* ctx    = (float*)(ws + 205553664);            // 524,288 B

    qkv_gemm<<<dim3(NPIX / BN, O3 / BM, NBATCH), 256, 0, stream>>>(x, w_qkv, qkv);
    ksoftmax_stats<<<NBATCH * 256, 256, 0, stream>>>(qkv, kmax, krecip);
    ctx_partial<<<dim3(8, NBATCH * HEADS), 256, 0, stream>>>(qkv, kmax, krecip, part);
    ctx_reduce<<<NBATCH * HEADS, 256, 0, stream>>>(part, ctx);
    out_fused<<<dim3(NPIX / PB, NBATCH), 256, 0, stream>>>(qkv, ctx, w_out, b_out, g, y);
}

// Round 2
// 271.975 us; speedup vs baseline: 2.8486x; 2.8486x over previous
//
#include <hip/hip_runtime.h>
#include <hip/hip_bf16.h>
#include <math.h>

// LinearAttention, bf16-MFMA pipeline.
// dims: B=16, C=256, H=W=64 (n=4096), HEADS=8, dh=32, HID=256, 3*HID=768.
//
// ws layout (bytes):
//   qkv_bf  @ 0          : 16*768*4096*2 = 100,663,296   (bf16)
//   xt      @ 100663296  : 16*4096*256*2 =  33,554,432   (bf16, [b][p][c])
//   wbf     @ 134217728  : (768*256 + 256*256)*2 = 524,288 (w_qkv_bf ++ w_out_bf)
//   kmax    @ 134742016  : 4096*4
//   krecip  @ 134758400  : 4096*4
//   part    @ 134774784  : 128*8*1024*4 = 4,194,304
//   ctx_t   @ 138969088  : 128*1024*4   = 524,288        ([bh][e*32+d])
//   out_t   @ 139493376  : 16*4096*256*2 = 33,554,432    (bf16, [b][p][e])
//   total ~173 MB

typedef __attribute__((ext_vector_type(8))) short bf16x8;
typedef __attribute__((ext_vector_type(4))) float f32x4;
typedef __attribute__((ext_vector_type(8))) unsigned short u16x8;

#define GL16(g, l) __builtin_amdgcn_global_load_lds( \
    (__attribute__((address_space(1))) void*)(void*)(g), \
    (__attribute__((address_space(3))) void*)(void*)(l), 16, 0, 0)

__device__ inline float b2f(unsigned short u) {
    union { float f; unsigned int i; } v; v.i = ((unsigned int)u) << 16; return v.f;
}
__device__ inline unsigned short f2b(float f) {
    union { float f; unsigned int i; } v; v.f = f;
    unsigned int r = v.i + 0x7fff + ((v.i >> 16) & 1);   // round-nearest-even
    return (unsigned short)(r >> 16);
}

// ---------------- K0w: weights fp32 -> bf16 (w_qkv then w_out, one arena) ----
__global__ __launch_bounds__(256) void conv_w(
    const float* __restrict__ wq, const float* __restrict__ wo,
    unsigned short* __restrict__ dst)
{
    int i4 = (blockIdx.x * 256 + threadIdx.x) * 4;   // 0..262140
    float4 v = (i4 < 196608) ? *(const float4*)&wq[i4]
                             : *(const float4*)&wo[i4 - 196608];
    unsigned int lo = (unsigned int)f2b(v.x) | ((unsigned int)f2b(v.y) << 16);
    unsigned int hi = (unsigned int)f2b(v.z) | ((unsigned int)f2b(v.w) << 16);
    *(uint2*)&dst[i4] = make_uint2(lo, hi);
}

// ---------------- K0x: x[b][c][p] fp32 -> xt[b][p][c] bf16 (tiled transpose) --
__global__ __launch_bounds__(256) void conv_x(
    const float* __restrict__ x, unsigned short* __restrict__ xt)
{
    __shared__ __align__(16) unsigned short T[64][72];
    const int t = threadIdx.x;
    const int p0 = blockIdx.x * 64, c0 = blockIdx.y * 64, b = blockIdx.z;
    const float* xb = x + ((size_t)b * 256 + c0) * 4096 + p0;
    #pragma unroll
    for (int i = 0; i < 4; ++i) {
        int flat = i * 256 + t;
        int cl = flat >> 4, p4 = (flat & 15) * 4;
        float4 v = *(const float4*)&xb[(size_t)cl * 4096 + p4];
        T[p4 + 0][cl] = f2b(v.x);
        T[p4 + 1][cl] = f2b(v.y);
        T[p4 + 2][cl] = f2b(v.z);
        T[p4 + 3][cl] = f2b(v.w);
    }
    __syncthreads();
    unsigned short* xtb = xt + ((size_t)b * 4096 + p0) * 256 + c0;
    #pragma unroll
    for (int j = 0; j < 2; ++j) {
        int flat = j * 256 + t;
        int row = flat >> 3, ch = flat & 7;
        uint4 v = *(const uint4*)&T[row][ch * 8];
        *(uint4*)&xtb[(size_t)row * 256 + ch * 8] = v;
    }
}

// ---------------- K1: qkv[b][o][p] = sum_c Wq[o][c] * X[b][c][p], bf16 MFMA ---
// A = Wq (rows o, K=c contiguous), B = xt (rows p, K=c contiguous).
// LDS rows = 128B (BK=64 bf16); chunk swizzle c^=(row&7): linear LDS dest,
// inverse-swizzled GLOBAL source, swizzled ds_read (guide rule 21).
__global__ __launch_bounds__(256) void qkv_mfma(
    const unsigned short* __restrict__ wq,   // [768][256] bf16
    const unsigned short* __restrict__ xt,   // [b][4096][256] bf16
    unsigned short* __restrict__ qkv)        // [b][768][4096] bf16
{
    __shared__ __align__(16) unsigned short As[128 * 64];   // 16 KB
    __shared__ __align__(16) unsigned short Bs[128 * 64];   // 16 KB
    const int t = threadIdx.x;
    const int l = t & 63, w = t >> 6;
    const int lm = l & 15, kg = l >> 4, le = l & 7, l3 = l >> 3;
    const int sx8 = (le ^ l3) * 8;          // source chunk (ushort units)
    const int p0 = blockIdx.x * 128, o0 = blockIdx.y * 128, b = blockIdx.z;
    const int wo = (w >> 1) * 64, wp = (w & 1) * 64;

    f32x4 acc[4][4] = {};
    const unsigned short* xb = xt + (size_t)b * 4096 * 256;

    for (int ks = 0; ks < 4; ++ks) {
        const int e0 = ks * 64;
        #pragma unroll
        for (int i = 0; i < 4; ++i) {
            int cid = w * 4 + i;            // 0..15, covers rows cid*8..+8
            int m = cid * 8 + l3;
            GL16(wq + (size_t)(o0 + m) * 256 + e0 + sx8, &As[cid * 512]);
            GL16(xb + (size_t)(p0 + m) * 256 + e0 + sx8, &Bs[cid * 512]);
        }
        __syncthreads();
        #pragma unroll
        for (int s = 0; s < 2; ++s) {
            bf16x8 af[4], bfr[4];
            #pragma unroll
            for (int mi = 0; mi < 4; ++mi) {
                int row = wo + mi * 16 + lm;
                int ch = ((s * 4 + kg) ^ (row & 7)) * 8;
                af[mi] = *(const bf16x8*)&As[row * 64 + ch];
            }
            #pragma unroll
            for (int ni = 0; ni < 4; ++ni) {
                int row = wp + ni * 16 + lm;
                int ch = ((s * 4 + kg) ^ (row & 7)) * 8;
                bfr[ni] = *(const bf16x8*)&Bs[row * 64 + ch];
            }
            #pragma unroll
            for (int mi = 0; mi < 4; ++mi)
                #pragma unroll
                for (int ni = 0; ni < 4; ++ni)
                    acc[mi][ni] = __builtin_amdgcn_mfma_f32_16x16x32_bf16(
                        af[mi], bfr[ni], acc[mi][ni], 0, 0, 0);
        }
        __syncthreads();
    }
    unsigned short* ob = qkv + (size_t)b * 768 * 4096;
    #pragma unroll
    for (int mi = 0; mi < 4; ++mi)
        #pragma unroll
        for (int ni = 0; ni < 4; ++ni) {
            int o = o0 + wo + mi * 16 + kg * 4;
            int p = p0 + wp + ni * 16 + lm;
            #pragma unroll
            for (int r = 0; r < 4; ++r)
                ob[(size_t)(o + r) * 4096 + p] = f2b(acc[mi][ni][r]);
        }
}

// ---------------- K2: k-softmax row stats (bf16 in) --------------------------
__global__ __launch_bounds__(256) void kstats(
    const unsigned short* __restrict__ qkv,
    float* __restrict__ kmax, float* __restrict__ krecip)
{
    const int row = blockIdx.x;              // b*256 + cd
    const int b = row >> 8, cd = row & 255;
    const int t = threadIdx.x;
    const unsigned short* kp = qkv + ((size_t)b * 768 + 256 + cd) * 4096 + t * 16;
    float v[16]; float m = -1e30f;
    u16x8 a0 = *(const u16x8*)kp;
    u16x8 a1 = *(const u16x8*)(kp + 8);
    #pragma unroll
    for (int i = 0; i < 8; ++i) { v[i] = b2f(a0[i]); v[8 + i] = b2f(a1[i]); }
    #pragma unroll
    for (int i = 0; i < 16; ++i) m = fmaxf(m, v[i]);
    #pragma unroll
    for (int off = 32; off > 0; off >>= 1) m = fmaxf(m, __shfl_xor(m, off));
    __shared__ float red[8];
    if ((t & 63) == 0) red[t >> 6] = m;
    __syncthreads();
    m = fmaxf(fmaxf(red[0], red[1]), fmaxf(red[2], red[3]));
    float s = 0.f;
    #pragma unroll
    for (int i = 0; i < 16; ++i) s += __expf(v[i] - m);
    #pragma unroll
    for (int off = 32; off > 0; off >>= 1) s += __shfl_xor(s, off);
    __syncthreads();
    if ((t & 63) == 0) red[4 + (t >> 6)] = s;
    __syncthreads();
    if (t == 0) {
        float S = red[4] + red[5] + red[6] + red[7];
        kmax[row] = m;
        krecip[row] = 1.0f / (S * 4096.0f);   // folds v/n
    }
}

// ---------------- K3: context partials (bf16 in) -----------------------------
__global__ __launch_bounds__(256) void ctx_partial(
    const unsigned short* __restrict__ qkv,
    const float* __restrict__ kmax, const float* __restrict__ krecip,
    float* __restrict__ part)
{
    const int seg = blockIdx.x, bh = blockIdx.y;
    const int b = bh >> 3, h = bh & 7;
    const int t = threadIdx.x;
    __shared__ float kc[32][65];
    __shared__ __align__(16) float vt[64][36];
    const unsigned short* kb = qkv + ((size_t)b * 768 + 256 + h * 32) * 4096;
    const unsigned short* vb = qkv + ((size_t)b * 768 + 512 + h * 32) * 4096;
    const int d = t >> 3, e0 = (t & 7) * 4;
    float a0 = 0, a1 = 0, a2 = 0, a3 = 0;

    for (int ch = 0; ch < 8; ++ch) {
        const int pb = seg * 512 + ch * 64;
        #pragma unroll
        for (int r = 0; r < 4; ++r) {
            int dd = r * 8 + (t >> 5);
            int pp = (t & 31) * 2;
            unsigned int kraw = *(const unsigned int*)&kb[(size_t)dd * 4096 + pb + pp];
            float mx = kmax[bh * 32 + dd], rc = krecip[bh * 32 + dd];
            kc[dd][pp]     = __expf(b2f((unsigned short)(kraw & 0xffff)) - mx) * rc;
            kc[dd][pp + 1] = __expf(b2f((unsigned short)(kraw >> 16)) - mx) * rc;
            unsigned int vraw = *(const unsigned int*)&vb[(size_t)dd * 4096 + pb + pp];
            vt[pp][dd]     = b2f((unsigned short)(vraw & 0xffff));
            vt[pp + 1][dd] = b2f((unsigned short)(vraw >> 16));
        }
        __syncthreads();
        #pragma unroll
        for (int pp = 0; pp < 64; ++pp) {
            float kd = kc[d][pp];
            float4 v4 = *(const float4*)&vt[pp][e0];
            a0 += kd * v4.x; a1 += kd * v4.y; a2 += kd * v4.z; a3 += kd * v4.w;
        }
        __syncthreads();
    }
    float* pp = part + ((size_t)(bh * 8 + seg) * 32 + d) * 32 + e0;
    pp[0] = a0; pp[1] = a1; pp[2] = a2; pp[3] = a3;
}

// ---------------- K3b: reduce partials; write ctx_t[bh][e*32+d] --------------
__global__ __launch_bounds__(256) void ctx_reduce(
    const float* __restrict__ part, float* __restrict__ ctxt)
{
    const int bh = blockIdx.x; const int t = threadIdx.x;
    #pragma unroll
    for (int r = 0; r < 4; ++r) {
        int idx = r * 256 + t;
        int d = idx >> 5, e = idx & 31;
        float s = 0.f;
        #pragma unroll
        for (int sg = 0; sg < 8; ++sg) s += part[((size_t)bh * 8 + sg) * 1024 + idx];
        ctxt[(size_t)bh * 1024 + e * 32 + d] = s;
    }
}

// ---------------- K4a: q-softmax + ctx matvec -> out_t[b][p][e] bf16 ---------
__global__ __launch_bounds__(256) void qctx(
    const unsigned short* __restrict__ qkv,
    const float* __restrict__ ctxt,
    unsigned short* __restrict__ outt)
{
    __shared__ __align__(16) float ctx_s[8192];        // [h][e*32+d], 32 KB
    __shared__ unsigned short out_s[64][258];          // [p][e256], 33 KB
    const int t = threadIdx.x;
    const int pb = blockIdx.x * 64, b = blockIdx.y;
    {
        const float4* src = (const float4*)(ctxt + (size_t)b * 8192);
        float4* dst = (float4*)ctx_s;
        #pragma unroll
        for (int i = 0; i < 8; ++i) dst[i * 256 + t] = src[i * 256 + t];
    }
    __syncthreads();
    const int w = t >> 6, p = t & 63;
    const float scale = 0.17677669529663689f;          // dh^-0.5
    #pragma unroll
    for (int hh = 0; hh < 2; ++hh) {
        const int h = w * 2 + hh;
        const unsigned short* qb = qkv + ((size_t)b * 768 + h * 32) * 4096 + pb + p;
        float ex[32]; float m = -1e30f;
        #pragma unroll
        for (int d = 0; d < 32; ++d) { ex[d] = b2f(qb[(size_t)d * 4096]); m = fmaxf(m, ex[d]); }
        float s = 0.f;
        #pragma unroll
        for (int d = 0; d < 32; ++d) { ex[d] = __expf(ex[d] - m); s += ex[d]; }
        const float inv = scale / s;
        const float* cb = ctx_s + h * 1024;
        #pragma unroll
        for (int e = 0; e < 32; ++e) {
            const float4* cr = (const float4*)(cb + e * 32);   // broadcast reads
            float a = 0.f;
            #pragma unroll
            for (int d4 = 0; d4 < 8; ++d4) {
                float4 c4 = cr[d4];
                a += c4.x * ex[d4 * 4] + c4.y * ex[d4 * 4 + 1]
                   + c4.z * ex[d4 * 4 + 2] + c4.w * ex[d4 * 4 + 3];
            }
            out_s[p][h * 32 + e] = f2b(a * inv);
        }
    }
    __syncthreads();
    unsigned int* ob = (unsigned int*)outt;
    #pragma unroll
    for (int j = 0; j < 32; ++j) {
        int flat = j * 256 + t;
        int row = flat >> 7, cw = flat & 127;
        unsigned int v = *(const unsigned int*)&out_s[row][cw * 2];
        ob[(size_t)(b * 4096 + pb + row) * 128 + cw] = v;
    }
}

// ---------------- K4b: y = Wout*out + b_out, fused LayerNorm, MFMA -----------
// BM=256 (all c in-block -> LN fuses), BN=64 p, BK=64, 4 waves (wave w: c rows w*64..+64).
__global__ __launch_bounds__(256) void proj_ln(
    const unsigned short* __restrict__ woutb,   // [256][256] bf16
    const unsigned short* __restrict__ outt,    // [b][4096][256] bf16
    const float* __restrict__ b_out, const float* __restrict__ g,
    float* __restrict__ y)
{
    __shared__ __align__(16) unsigned short As[256 * 64];   // 32 KB
    __shared__ __align__(16) unsigned short Bs[64 * 64];    // 8 KB
    __shared__ float red1[4][64], red2[4][64], mean_s[64], rstd_s[64];
    const int t = threadIdx.x;
    const int l = t & 63, w = t >> 6;
    const int lm = l & 15, kg = l >> 4, le = l & 7, l3 = l >> 3;
    const int sx8 = (le ^ l3) * 8;
    const int pb = blockIdx.x * 64, b = blockIdx.y;

    f32x4 acc[4][4] = {};
    const unsigned short* outb = outt + (size_t)b * 4096 * 256;

    for (int ks = 0; ks < 4; ++ks) {
        const int e0 = ks * 64;
        #pragma unroll
        for (int i = 0; i < 8; ++i) {
            int cid = w * 8 + i;                 // 0..31
            int m = cid * 8 + l3;                // c row 0..255
            GL16(woutb + (size_t)m * 256 + e0 + sx8, &As[cid * 512]);
        }
        #pragma unroll
        for (int i = 0; i < 2; ++i) {
            int cid = w * 2 + i;                 // 0..7
            int m = cid * 8 + l3;                // p row 0..63
            GL16(outb + (size_t)(pb + m) * 256 + e0 + sx8, &Bs[cid * 512]);
        }
        __syncthreads();
        #pragma unroll
        for (int s = 0; s < 2; ++s) {
            bf16x8 af[4], bfr[4];
            #pragma unroll
            for (int mi = 0; mi < 4; ++mi) {
                int row = w * 64 + mi * 16 + lm;
                int ch = ((s * 4 + kg) ^ (row & 7)) * 8;
                af[mi] = *(const bf16x8*)&As[row * 64 + ch];
            }
            #pragma unroll
            for (int ni = 0; ni < 4; ++ni) {
                int row = ni * 16 + lm;
                int ch = ((s * 4 + kg) ^ (row & 7)) * 8;
                bfr[ni] = *(const bf16x8*)&Bs[row * 64 + ch];
            }
            #pragma unroll
            for (int mi = 0; mi < 4; ++mi)
                #pragma unroll
                for (int ni = 0; ni < 4; ++ni)
                    acc[mi][ni] = __builtin_amdgcn_mfma_f32_16x16x32_bf16(
                        af[mi], bfr[ni], acc[mi][ni], 0, 0, 0);
        }
        __syncthreads();
    }
    // bias + gamma (c = w*64 + mi*16 + kg*4 + r)
    float bo[4][4], gv[4][4];
    #pragma unroll
    for (int mi = 0; mi < 4; ++mi)
        #pragma unroll
        for (int r = 0; r < 4; ++r) {
            int c = w * 64 + mi * 16 + kg * 4 + r;
            bo[mi][r] = b_out[c]; gv[mi][r] = g[c];
        }
    #pragma unroll
    for (int mi = 0; mi < 4; ++mi)
        #pragma unroll
        for (int ni = 0; ni < 4; ++ni)
            #pragma unroll
            for (int r = 0; r < 4; ++r)
                acc[mi][ni][r] += bo[mi][r];
    // LN stats: per p (col), sum over 256 c (16 in-lane, x4 lane groups, x4 waves)
    #pragma unroll
    for (int ni = 0; ni < 4; ++ni) {
        float s1 = 0.f, s2 = 0.f;
        #pragma unroll
        for (int mi = 0; mi < 4; ++mi)
            #pragma unroll
            for (int r = 0; r < 4; ++r) { float v = acc[mi][ni][r]; s1 += v; s2 += v * v; }
        s1 += __shfl_xor(s1, 16); s2 += __shfl_xor(s2, 16);
        s1 += __shfl_xor(s1, 32); s2 += __shfl_xor(s2, 32);
        if (kg == 0) { red1[w][ni * 16 + lm] = s1; red2[w][ni * 16 + lm] = s2; }
    }
    __syncthreads();
    if (t < 64) {
        float s1 = red1[0][t] + red1[1][t] + red1[2][t] + red1[3][t];
        float s2 = red2[0][t] + red2[1][t] + red2[2][t] + red2[3][t];
        float mn = s1 * (1.f / 256.f);
        float var = s2 * (1.f / 256.f) - mn * mn;
        mean_s[t] = mn; rstd_s[t] = rsqrtf(var + 1e-5f);
    }
    __syncthreads();
    float* yb = y + (size_t)b * 256 * 4096 + pb;
    #pragma unroll
    for (int ni = 0; ni < 4; ++ni) {
        int p = ni * 16 + lm;
        float mn = mean_s[p], rs = rstd_s[p];
        #pragma unroll
        for (int mi = 0; mi < 4; ++mi) {
            int c = w * 64 + mi * 16 + kg * 4;
            #pragma unroll
            for (int r = 0; r < 4; ++r)
                yb[(size_t)(c + r) * 4096 + p] = (acc[mi][ni][r] - mn) * rs * gv[mi][r];
        }
    }
}

extern "C" void kernel_launch(void* const* d_in, const int* in_sizes, int n_in,
                              void* d_out, int out_size, void* d_ws, size_t ws_size,
                              hipStream_t stream) {
    const float* x     = (const float*)d_in[0];
    const float* w_qkv = (const float*)d_in[1];
    const float* w_out = (const float*)d_in[2];
    const float* b_out = (const float*)d_in[3];
    const float* g     = (const float*)d_in[4];
    float* y = (float*)d_out;

    char* ws = (char*)d_ws;
    unsigned short* qkvb  = (unsigned short*)ws;                    // 100,663,296
    unsigned short* xt    = (unsigned short*)(ws + 100663296);      //  33,554,432
    unsigned short* wbf   = (unsigned short*)(ws + 134217728);      //     524,288
    float*          kmax  = (float*)(ws + 134742016);               //      16,384
    float*          krec  = (float*)(ws + 134758400);               //      16,384
    float*          part  = (float*)(ws + 134774784);               //   4,194,304
    float*          ctxt  = (float*)(ws + 138969088);               //     524,288
    unsigned short* outt  = (unsigned short*)(ws + 139493376);      //  33,554,432

    conv_w<<<256, 256, 0, stream>>>(w_qkv, w_out, wbf);
    conv_x<<<dim3(64, 4, 16), 256, 0, stream>>>(x, xt);
    qkv_mfma<<<dim3(32, 6, 16), 256, 0, stream>>>(wbf, xt, qkvb);
    kstats<<<4096, 256, 0, stream>>>(qkvb, kmax, krec);
    ctx_partial<<<dim3(8, 128), 256, 0, stream>>>(qkvb, kmax, krec, part);
    ctx_reduce<<<128, 256, 0, stream>>>(part, ctxt);
    qctx<<<dim3(64, 16), 256, 0, stream>>>(qkvb, ctxt, outt);
    proj_ln<<<dim3(64, 16), 256, 0, stream>>>(wbf + 196608, outt, b_out, g, y);
}